// Round 7
// baseline (260.341 us; speedup 1.0000x reference)
//
#include <hip/hip_runtime.h>
#include <hip/hip_bf16.h>
#include <cstdint>
#include <cstddef>

// Problem constants
constexpr int T = 8;
constexpr int C = 256;     // feature channels = GEMM K
constexpr int N = 4096;    // H*W pixels per frame
constexpr int CAP = 4232;  // packed rows per frame: >= roundup(nfg,8)+roundup(nbg,128), mult of 8
constexpr float TEMP_INV = 14.285714285714286f;  // 1/0.07
constexpr float EPS = 1e-8f;

typedef __bf16 bf16;
typedef __bf16 bf16x8 __attribute__((ext_vector_type(8)));
typedef float floatx4 __attribute__((ext_vector_type(4)));

// ---------------------------------------------------------------------------
// async global->LDS, 16B per lane, wave-uniform LDS base + lane*16
__device__ __forceinline__ void async_copy16(const bf16* g, bf16* l) {
    __builtin_amdgcn_global_load_lds((const __attribute__((address_space(1))) void*)g,
                                     (__attribute__((address_space(3))) void*)l,
                                     16, 0, 0);
}

// ---------------------------------------------------------------------------
// PACK = prep + normalize fused (node-count reduction; R3 measured ~10us/node).
// 512 blocks x 256 threads; block = (frame t = blockIdx&7, slice n0 of 64 pixels).
// Each block recomputes its frame's dice sums from cur/hist (8K floats, L2-hot)
// PLUS prefix-fg counts for pixels < n0 -> deterministic rank bases with NO
// atomics and no rankmap buffer. Then: labels, negbuf zero, normalize, swizzled
// compacted scatter to fpack, posc, and gap-row zeroing [bbase+nbg, CAP).
__global__ __launch_bounds__(256, 4) void pack_kernel(const float* __restrict__ cur,
                                                      const float* __restrict__ hist,
                                                      const float* __restrict__ feat,
                                                      float* __restrict__ out_labels,
                                                      float* __restrict__ negbuf,
                                                      bf16* __restrict__ fpack,
                                                      float* __restrict__ posc,
                                                      int* __restrict__ nfg,
                                                      int* __restrict__ nbg,
                                                      int* __restrict__ done_ctr) {
    __shared__ bf16 tile[64 * 258];    // [n][c], true chunk order, pad 258
    __shared__ float partial[256];
    __shared__ float rbuf[4][5];
    __shared__ float rnorm_s[64];
    __shared__ unsigned short rk_s[64];
    int t = blockIdx.x & 7;            // frame -> XCD pin (matches sim)
    int s = blockIdx.x >> 3;           // slice 0..63
    int n0 = s * 64;
    int tid = threadIdx.x;
    int lane = tid & 63;
    int w = tid >> 6;

    // ----- Phase 1: frame-wide dice sums + prefix-fg counts (pixels < n0) -----
    const float* cb_ = cur + t * N;
    const float* hb_ = hist + t * N;
    float e1 = 0.f, sc = 0.f, sh = 0.f, pc = 0.f, ph = 0.f;
    for (int p = tid; p < N; p += 256) {
        float c = cb_[p], h = hb_[p];
        float cb = c > 0.5f ? 1.f : 0.f;
        float hb = h > 0.5f ? 1.f : 0.f;
        e1 += cb * hb; sc += cb; sh += hb;
        if (p < n0) { pc += cb; ph += hb; }
    }
    for (int o = 32; o > 0; o >>= 1) {
        e1 += __shfl_down(e1, o);
        sc += __shfl_down(sc, o);
        sh += __shfl_down(sh, o);
        pc += __shfl_down(pc, o);
        ph += __shfl_down(ph, o);
    }
    if (lane == 0) { rbuf[w][0]=e1; rbuf[w][1]=sc; rbuf[w][2]=sh; rbuf[w][3]=pc; rbuf[w][4]=ph; }
    __syncthreads();
    float E1 = rbuf[0][0]+rbuf[1][0]+rbuf[2][0]+rbuf[3][0];
    float SC = rbuf[0][1]+rbuf[1][1]+rbuf[2][1]+rbuf[3][1];
    float SH = rbuf[0][2]+rbuf[1][2]+rbuf[2][2]+rbuf[3][2];
    float PC = rbuf[0][3]+rbuf[1][3]+rbuf[2][3]+rbuf[3][3];
    float PH = rbuf[0][4]+rbuf[1][4]+rbuf[2][4]+rbuf[3][4];
    float E2 = SC + SH;
    float m1 = (2.f * E1 + EPS) / (E2 + EPS);
    float m2 = (E1 + EPS) / (E2 - E1 + EPS);
    float dev = 1.f - 0.5f * (m1 + m2);
    bool uc = (dev <= 0.0f);
    int nfgt  = (int)(uc ? SC : SH);   // exact: integer-valued fp32 <= 4096
    int nbgt  = N - nfgt;
    int bbase = (nfgt + 7) & ~7;
    int basef = (int)(uc ? PC : PH);   // fg rank base for this slice
    int baseb = n0 - basef;            // bg rank base

    if (blockIdx.x < 8 && tid == 0) { nfg[t] = nfgt; nbg[t] = nbgt; }
    if (blockIdx.x == 0 && tid == 0) { *done_ctr = 0; }   // reset for sim's fused loss

    // ----- Phase 2: labels + negbuf zero + deterministic ranks (wave 0) -----
    if (tid < 64) {
        int p = n0 + tid;
        float lab = uc ? cb_[p] : hb_[p];
        out_labels[t * N + p] = lab;
        negbuf[t * N + p] = 0.f;
        bool fg = lab > 0.5f;
        unsigned long long b = __ballot(fg);   // wave 0 fully active here
        unsigned long long lowmask = (tid == 63) ? 0x7fffffffffffffffull
                                                 : ((1ull << tid) - 1ull);
        int rfg = __popcll(b & lowmask);
        int rbg = __popcll((~b) & lowmask);
        int rank = fg ? (basef + rfg) : (baseb + rbg);
        rk_s[tid] = (unsigned short)(rank | (fg ? 0x8000 : 0));
    }
    __syncthreads();

    // ----- Phase 3: normalize + bf16 cast (round-0 body, local ranks) -----
    const float* fb = feat + (size_t)t * C * N;
    float ss = 0.f;
    #pragma unroll 16
    for (int it = 0; it < 64; ++it) {
        int c = w * 64 + it;
        float v = fb[(size_t)c * N + n0 + lane];
        ss += v * v;
        tile[lane * 258 + c] = (bf16)v;
    }
    partial[tid] = ss;
    __syncthreads();
    if (tid < 64) {
        float sv = partial[tid] + partial[tid + 64] + partial[tid + 128] + partial[tid + 192];
        float r = 1.f / fmaxf(sqrtf(sv), 1e-12f);
        rnorm_s[tid] = r;
        unsigned short rk = rk_s[tid];
        if (rk & 0x8000) posc[t * N + (rk & 0x7fff)] = sv * r * r;  // fg only
    }
    __syncthreads();
    bf16* fp = fpack + (size_t)t * CAP * C;
    #pragma unroll
    for (int it = 0; it < 8; ++it) {
        int l = it * 256 + tid;        // short8 index, 0..2047
        int n = l >> 5;                // tile row (pixel)
        int c8 = l & 31;               // true 16B-chunk index 0..31
        unsigned short rk = rk_s[n];
        int r_pack = (rk & 0x7fff) + ((rk & 0x8000) ? 0 : bbase);
        int slot = (c8 & ~7) | ((c8 & 7) ^ (r_pack & 7));   // swizzled store pos
        float r = rnorm_s[n];
        bf16x8 vin = *(const bf16x8*)&tile[n * 258 + c8 * 8];
        bf16x8 vo;
        for (int j = 0; j < 8; ++j) vo[j] = (bf16)((float)vin[j] * r);
        *(bf16x8*)(fp + (size_t)r_pack * C + slot * 8) = vo;
    }

    // ----- Phase 4: zero gap rows [bbase+nbg, CAP) (disjoint from all scatter) -----
    int gstart = bbase + nbgt;                 // in [4096, 4103]
    int nch = (CAP - gstart) * 32;             // float4 chunks
    float4 z4 = make_float4(0.f, 0.f, 0.f, 0.f);
    float4* pz = (float4*)(fpack + ((size_t)t * CAP + gstart) * C);
    for (int i = s * 256 + tid; i < nch; i += 64 * 256) pz[i] = z4;
}

// ---------------------------------------------------------------------------
// Fused sim GEMM + exp + row reduction + (last-block) final loss.
// GEMM body is byte-identical to the proven round-0 structure. Every block
// increments done_ctr exactly once; the last one computes the loss.
__global__ __launch_bounds__(256, 3) void sim_kernel(const bf16* __restrict__ fpack,
                                                     const int* __restrict__ nfg,
                                                     const int* __restrict__ nbg,
                                                     float* __restrict__ neg,
                                                     const float* __restrict__ posc,
                                                     int* __restrict__ done_ctr,
                                                     float* __restrict__ out_loss) {
    int t = blockIdx.x & 7;            // frame -> XCD pin (8 XCDs)
    int wid = blockIdx.x >> 3;         // 0..271
    int tid = threadIdx.x;
    int lane = tid & 63;
    int w = tid >> 6;
    int nfgt = nfg[t];
    int nbgt = nbg[t];
    bool active = (nfgt > 0 && nbgt > 0);
    if (active) {
        int nr = (nfgt + 127) >> 7;
        int nc = (nbgt + 127) >> 7;
        active = (wid < nr * nc);
        if (active) {
            int rowbase = (wid / nc) * 128;
            int colbase = (wid % nc) * 128;
            int bbase = (nfgt + 7) & ~7;

            __shared__ bf16 a_lds[128 * 64];
            __shared__ bf16 b_lds[128 * 64];
            const bf16* fb = fpack + (size_t)t * CAP * C;

            int lrow = lane >> 3;
            int lchunk = lane & 7;
            int r0w = (w & 1) * 64;
            int c0w = (w >> 1) * 64;

            floatx4 acc[4][4];
            for (int i = 0; i < 4; ++i)
                for (int j = 0; j < 4; ++j)
                    acc[i][j] = (floatx4){0.f, 0.f, 0.f, 0.f};

            for (int ks = 0; ks < 4; ++ks) {
                int k0 = ks * 64;
                __syncthreads();
                for (int s = 0; s < 4; ++s) {
                    int q = w * 4 + s;
                    int ra = rowbase + q * 8 + lrow;
                    int rb = bbase + colbase + q * 8 + lrow;
                    async_copy16(fb + (size_t)ra * C + k0 + lchunk * 8, &a_lds[q * 512]);
                    async_copy16(fb + (size_t)rb * C + k0 + lchunk * 8, &b_lds[q * 512]);
                }
                __syncthreads();
                for (int kk = 0; kk < 64; kk += 32) {
                    int quad = lane >> 4;
                    int chread = (kk >> 3) + quad;
                    bf16x8 af[4], bfr[4];
                    for (int i = 0; i < 4; ++i) {
                        int r = r0w + 16 * i + (lane & 15);
                        int chs = chread ^ (r & 7);
                        af[i] = *(const bf16x8*)&a_lds[r * 64 + chs * 8];
                    }
                    for (int j = 0; j < 4; ++j) {
                        int cidx = c0w + 16 * j + (lane & 15);
                        int chs = chread ^ (cidx & 7);
                        bfr[j] = *(const bf16x8*)&b_lds[cidx * 64 + chs * 8];
                    }
                    for (int i = 0; i < 4; ++i)
                        for (int j = 0; j < 4; ++j)
                            acc[i][j] = __builtin_amdgcn_mfma_f32_16x16x32_bf16(af[i], bfr[j], acc[i][j], 0, 0, 0);
                }
            }

            float bgv[4];
            for (int j = 0; j < 4; ++j) {
                int cidx = colbase + c0w + 16 * j + (lane & 15);
                bgv[j] = (cidx < nbgt) ? 1.f : 0.f;
            }
            int quad = lane >> 4;
            for (int i = 0; i < 4; ++i) {
                for (int reg = 0; reg < 4; ++reg) {
                    float msum = 0.f;
                    for (int j = 0; j < 4; ++j)
                        msum += __expf(acc[i][j][reg] * TEMP_INV) * bgv[j];
                    msum += __shfl_xor(msum, 1);
                    msum += __shfl_xor(msum, 2);
                    msum += __shfl_xor(msum, 4);
                    msum += __shfl_xor(msum, 8);
                    if ((lane & 15) == 0) {
                        int row = rowbase + r0w + 16 * i + quad * 4 + reg;
                        if (row < nfgt) atomicAdd(&neg[t * N + row], msum);
                    }
                }
            }
        }
    }

    // ----- completion counter + fused final loss (last block only) -----
    __threadfence();                   // release: neg updates visible before bump
    __shared__ int lastflag;
    if (tid == 0) {
        int old = atomicAdd(done_ctr, 1);
        lastflag = (old == (int)gridDim.x - 1) ? 1 : 0;
    }
    __syncthreads();
    if (lastflag) {
        __threadfence();               // acquire: see all blocks' neg updates
        __shared__ float fl[8], vv[8];
        for (int tf = w; tf < 8; tf += 4) {   // wave w -> frames w, w+4
            int nf = nfg[tf];
            float s = 0.f;
            #pragma unroll 4
            for (int k = lane; k < nf; k += 64) {
                float pos = __expf(posc[tf * N + k] * TEMP_INV);
                float ng = neg[tf * N + k];
                s += logf((pos + ng + EPS) / pos);
            }
            for (int o = 32; o > 0; o >>= 1) s += __shfl_down(s, o);
            if (lane == 0) {
                float valid = (nf > 0 && nbg[tf] > 0) ? 1.f : 0.f;
                fl[tf] = valid * (s / fmaxf((float)nf, 1.f));
                vv[tf] = valid;
            }
        }
        __syncthreads();
        if (tid == 0) {
            float ls = 0.f, v = 0.f;
            for (int i = 0; i < T; ++i) { ls += fl[i]; v += vv[i]; }
            out_loss[0] = (v > 0.f) ? ls / fmaxf(v, 1.f) : 0.f;
        }
    }
}

// ---------------------------------------------------------------------------
extern "C" void kernel_launch(void* const* d_in, const int* in_sizes, int n_in,
                              void* d_out, int out_size, void* d_ws, size_t ws_size,
                              hipStream_t stream) {
    const float* cur  = (const float*)d_in[0];
    const float* hist = (const float*)d_in[1];
    const float* feat = (const float*)d_in[2];
    float* out = (float*)d_out;   // labels[32768] ++ loss[1]

    char* ws = (char*)d_ws;
    bf16*  fpack   = (bf16*)ws;                           // T*CAP*C bf16 = 17.33 MB
    size_t off = (size_t)T * CAP * C * sizeof(bf16);      // 17334272
    float* negbuf  = (float*)(ws + off);  off += (size_t)T * N * 4;   // 131072
    float* posc    = (float*)(ws + off);  off += (size_t)T * N * 4;   // 131072
    int*   nfg     = (int*)(ws + off);    off += 8 * 4;
    int*   nbg     = (int*)(ws + off);    off += 8 * 4;
    int*   done_ctr = (int*)(ws + off);

    pack_kernel<<<512, 256, 0, stream>>>(cur, hist, feat, out, negbuf, fpack,
                                         posc, nfg, nbg, done_ctr);
    sim_kernel<<<2176, 256, 0, stream>>>(fpack, nfg, nbg, negbuf, posc,
                                         done_ctr, out + 32768);
}

// Round 8
// 147.860 us; speedup vs baseline: 1.7607x; 1.7607x over previous
//
#include <hip/hip_runtime.h>
#include <hip/hip_bf16.h>
#include <cstdint>
#include <cstddef>

// Problem constants
constexpr int T = 8;
constexpr int C = 256;     // feature channels = GEMM K
constexpr int N = 4096;    // H*W pixels per frame
constexpr int CAP = 4232;  // packed rows per frame: >= roundup(nfg,8)+roundup(nbg,128), mult of 8
constexpr float TEMP_INV = 14.285714285714286f;  // 1/0.07
constexpr float EPS = 1e-8f;

typedef __bf16 bf16;
typedef __bf16 bf16x8 __attribute__((ext_vector_type(8)));
typedef float floatx4 __attribute__((ext_vector_type(4)));

// ---------------------------------------------------------------------------
// async global->LDS, 16B per lane, wave-uniform LDS base + lane*16
__device__ __forceinline__ void async_copy16(const bf16* g, bf16* l) {
    __builtin_amdgcn_global_load_lds((const __attribute__((address_space(1))) void*)g,
                                     (__attribute__((address_space(3))) void*)l,
                                     16, 0, 0);
}

// ---------------------------------------------------------------------------
// PACK = prep + normalize fused. 512 blocks x 256 threads;
// block = (frame t = blockIdx&7, slice n0 of 64 pixels).
// Each block recomputes its frame's dice sums from cur/hist (L2-hot after the
// first block touches them) PLUS prefix-fg counts for pixels < n0 ->
// deterministic rank bases with NO atomics and no rankmap buffer. Then:
// labels, negbuf zero, normalize, swizzled compacted scatter to fpack, posc,
// and gap-row zeroing [bbase+nbg, CAP).
// NOTE (R7 lesson): no __threadfence anywhere — per-block device fences
// invalidate the shared per-XCD L2 and tripled the downstream GEMM.
__global__ __launch_bounds__(256, 4) void pack_kernel(const float* __restrict__ cur,
                                                      const float* __restrict__ hist,
                                                      const float* __restrict__ feat,
                                                      float* __restrict__ out_labels,
                                                      float* __restrict__ negbuf,
                                                      bf16* __restrict__ fpack,
                                                      float* __restrict__ posc,
                                                      int* __restrict__ nfg,
                                                      int* __restrict__ nbg) {
    __shared__ bf16 tile[64 * 258];    // [n][c], true chunk order, pad 258
    __shared__ float partial[256];
    __shared__ float rbuf[4][5];
    __shared__ float rnorm_s[64];
    __shared__ unsigned short rk_s[64];
    int t = blockIdx.x & 7;            // frame -> XCD pin (matches sim)
    int s = blockIdx.x >> 3;           // slice 0..63
    int n0 = s * 64;
    int tid = threadIdx.x;
    int lane = tid & 63;
    int w = tid >> 6;

    // ----- Phase 1: frame-wide dice sums + prefix-fg counts (pixels < n0) -----
    const float* cb_ = cur + t * N;
    const float* hb_ = hist + t * N;
    float e1 = 0.f, sc = 0.f, sh = 0.f, pc = 0.f, ph = 0.f;
    for (int p = tid; p < N; p += 256) {
        float c = cb_[p], h = hb_[p];
        float cb = c > 0.5f ? 1.f : 0.f;
        float hb = h > 0.5f ? 1.f : 0.f;
        e1 += cb * hb; sc += cb; sh += hb;
        if (p < n0) { pc += cb; ph += hb; }
    }
    for (int o = 32; o > 0; o >>= 1) {
        e1 += __shfl_down(e1, o);
        sc += __shfl_down(sc, o);
        sh += __shfl_down(sh, o);
        pc += __shfl_down(pc, o);
        ph += __shfl_down(ph, o);
    }
    if (lane == 0) { rbuf[w][0]=e1; rbuf[w][1]=sc; rbuf[w][2]=sh; rbuf[w][3]=pc; rbuf[w][4]=ph; }
    __syncthreads();
    float E1 = rbuf[0][0]+rbuf[1][0]+rbuf[2][0]+rbuf[3][0];
    float SC = rbuf[0][1]+rbuf[1][1]+rbuf[2][1]+rbuf[3][1];
    float SH = rbuf[0][2]+rbuf[1][2]+rbuf[2][2]+rbuf[3][2];
    float PC = rbuf[0][3]+rbuf[1][3]+rbuf[2][3]+rbuf[3][3];
    float PH = rbuf[0][4]+rbuf[1][4]+rbuf[2][4]+rbuf[3][4];
    float E2 = SC + SH;
    float m1 = (2.f * E1 + EPS) / (E2 + EPS);
    float m2 = (E1 + EPS) / (E2 - E1 + EPS);
    float dev = 1.f - 0.5f * (m1 + m2);
    bool uc = (dev <= 0.0f);
    int nfgt  = (int)(uc ? SC : SH);   // exact: integer-valued fp32 <= 4096
    int nbgt  = N - nfgt;
    int bbase = (nfgt + 7) & ~7;
    int basef = (int)(uc ? PC : PH);   // fg rank base for this slice
    int baseb = n0 - basef;            // bg rank base

    if (blockIdx.x < 8 && tid == 0) { nfg[t] = nfgt; nbg[t] = nbgt; }

    // ----- Phase 2: labels + negbuf zero + deterministic ranks (wave 0) -----
    if (tid < 64) {
        int p = n0 + tid;
        float lab = uc ? cb_[p] : hb_[p];
        out_labels[t * N + p] = lab;
        negbuf[t * N + p] = 0.f;
        bool fg = lab > 0.5f;
        unsigned long long b = __ballot(fg);   // wave 0 fully active here
        unsigned long long lowmask = (tid == 63) ? 0x7fffffffffffffffull
                                                 : ((1ull << tid) - 1ull);
        int rfg = __popcll(b & lowmask);
        int rbg = __popcll((~b) & lowmask);
        int rank = fg ? (basef + rfg) : (baseb + rbg);
        rk_s[tid] = (unsigned short)(rank | (fg ? 0x8000 : 0));
    }
    __syncthreads();

    // ----- Phase 3: normalize + bf16 cast (round-0 body, local ranks) -----
    const float* fb = feat + (size_t)t * C * N;
    float ss = 0.f;
    #pragma unroll 16
    for (int it = 0; it < 64; ++it) {
        int c = w * 64 + it;
        float v = fb[(size_t)c * N + n0 + lane];
        ss += v * v;
        tile[lane * 258 + c] = (bf16)v;
    }
    partial[tid] = ss;
    __syncthreads();
    if (tid < 64) {
        float sv = partial[tid] + partial[tid + 64] + partial[tid + 128] + partial[tid + 192];
        float r = 1.f / fmaxf(sqrtf(sv), 1e-12f);
        rnorm_s[tid] = r;
        unsigned short rk = rk_s[tid];
        if (rk & 0x8000) posc[t * N + (rk & 0x7fff)] = sv * r * r;  // fg only
    }
    __syncthreads();
    bf16* fp = fpack + (size_t)t * CAP * C;
    #pragma unroll
    for (int it = 0; it < 8; ++it) {
        int l = it * 256 + tid;        // short8 index, 0..2047
        int n = l >> 5;                // tile row (pixel)
        int c8 = l & 31;               // true 16B-chunk index 0..31
        unsigned short rk = rk_s[n];
        int r_pack = (rk & 0x7fff) + ((rk & 0x8000) ? 0 : bbase);
        int slot = (c8 & ~7) | ((c8 & 7) ^ (r_pack & 7));   // swizzled store pos
        float r = rnorm_s[n];
        bf16x8 vin = *(const bf16x8*)&tile[n * 258 + c8 * 8];
        bf16x8 vo;
        for (int j = 0; j < 8; ++j) vo[j] = (bf16)((float)vin[j] * r);
        *(bf16x8*)(fp + (size_t)r_pack * C + slot * 8) = vo;
    }

    // ----- Phase 4: zero gap rows [bbase+nbg, CAP) (disjoint from all scatter) -----
    int gstart = bbase + nbgt;                 // in [4096, 4103]
    int nch = (CAP - gstart) * 32;             // float4 chunks
    float4 z4 = make_float4(0.f, 0.f, 0.f, 0.f);
    float4* pz = (float4*)(fpack + ((size_t)t * CAP + gstart) * C);
    for (int i = s * 256 + tid; i < nch; i += 64 * 256) pz[i] = z4;
}

// ---------------------------------------------------------------------------
// Fused sim GEMM + exp + row reduction over compacted fg rows x bg cols.
// EXACT round-5 body (54.7 us proven): single-buffer 32KB LDS, swizzled
// contiguous staging, 3 blocks/CU, fence-free, early-exit inactive blocks.
__global__ __launch_bounds__(256, 3) void sim_kernel(const bf16* __restrict__ fpack,
                                                     const int* __restrict__ nfg,
                                                     const int* __restrict__ nbg,
                                                     float* __restrict__ neg) {
    int t = blockIdx.x & 7;            // frame -> XCD pin (8 XCDs)
    int wid = blockIdx.x >> 3;         // 0..271
    int nfgt = nfg[t];
    int nbgt = nbg[t];
    if (nfgt <= 0 || nbgt <= 0) return;
    int nr = (nfgt + 127) >> 7;
    int nc = (nbgt + 127) >> 7;
    if (wid >= nr * nc) return;
    int rowbase = (wid / nc) * 128;
    int colbase = (wid % nc) * 128;
    int bbase = (nfgt + 7) & ~7;       // packed row where bg rows start

    __shared__ bf16 a_lds[128 * 64];
    __shared__ bf16 b_lds[128 * 64];
    int tid = threadIdx.x;
    int lane = tid & 63;
    int w = tid >> 6;
    const bf16* fb = fpack + (size_t)t * CAP * C;

    int lrow = lane >> 3;              // row within 8-row group
    int lchunk = lane & 7;             // 16B chunk within 128B subrow
    int r0w = (w & 1) * 64;
    int c0w = (w >> 1) * 64;

    floatx4 acc[4][4];
    for (int i = 0; i < 4; ++i)
        for (int j = 0; j < 4; ++j)
            acc[i][j] = (floatx4){0.f, 0.f, 0.f, 0.f};

    for (int ks = 0; ks < 4; ++ks) {
        int k0 = ks * 64;
        __syncthreads();
        for (int s = 0; s < 4; ++s) {
            int q = w * 4 + s;                 // 0..15
            int ra = rowbase + q * 8 + lrow;           // contiguous packed fg row
            int rb = bbase + colbase + q * 8 + lrow;   // contiguous packed bg row
            async_copy16(fb + (size_t)ra * C + k0 + lchunk * 8, &a_lds[q * 512]);
            async_copy16(fb + (size_t)rb * C + k0 + lchunk * 8, &b_lds[q * 512]);
        }
        __syncthreads();
        for (int kk = 0; kk < 64; kk += 32) {
            int quad = lane >> 4;
            int chread = (kk >> 3) + quad;     // wanted true chunk (0..7)
            bf16x8 af[4], bfr[4];
            for (int i = 0; i < 4; ++i) {
                int r = r0w + 16 * i + (lane & 15);
                int chs = chread ^ (r & 7);
                af[i] = *(const bf16x8*)&a_lds[r * 64 + chs * 8];
            }
            for (int j = 0; j < 4; ++j) {
                int cidx = c0w + 16 * j + (lane & 15);
                int chs = chread ^ (cidx & 7);
                bfr[j] = *(const bf16x8*)&b_lds[cidx * 64 + chs * 8];
            }
            for (int i = 0; i < 4; ++i)
                for (int j = 0; j < 4; ++j)
                    acc[i][j] = __builtin_amdgcn_mfma_f32_16x16x32_bf16(af[i], bfr[j], acc[i][j], 0, 0, 0);
        }
    }

    // epilogue: exp + row-sum; mask padded cols, guard padded rows
    float bgv[4];
    for (int j = 0; j < 4; ++j) {
        int cidx = colbase + c0w + 16 * j + (lane & 15);
        bgv[j] = (cidx < nbgt) ? 1.f : 0.f;
    }
    int quad = lane >> 4;
    for (int i = 0; i < 4; ++i) {
        for (int reg = 0; reg < 4; ++reg) {
            float msum = 0.f;
            for (int j = 0; j < 4; ++j)
                msum += __expf(acc[i][j][reg] * TEMP_INV) * bgv[j];
            msum += __shfl_xor(msum, 1);
            msum += __shfl_xor(msum, 2);
            msum += __shfl_xor(msum, 4);
            msum += __shfl_xor(msum, 8);
            if ((lane & 15) == 0) {
                int row = rowbase + r0w + 16 * i + quad * 4 + reg;   // compacted fg row
                if (row < nfgt) atomicAdd(&neg[t * N + row], msum);
            }
        }
    }
}

// ---------------------------------------------------------------------------
// Fused per-frame + final loss: 512 threads, wave t handles frame t.
// All reads contiguous (neg and pos both compacted by fg rank).
__global__ void loss_kernel(const float* __restrict__ negbuf,
                            const float* __restrict__ posc,
                            const int* __restrict__ nfg,
                            const int* __restrict__ nbg,
                            float* __restrict__ out_loss) {
    int tid = threadIdx.x;
    int t = tid >> 6;
    int lane = tid & 63;
    int nfgt = nfg[t];
    float s = 0.f;
    #pragma unroll 4
    for (int k = lane; k < nfgt; k += 64) {
        float pos = __expf(posc[t * N + k] * TEMP_INV);
        float ng = negbuf[t * N + k];
        s += logf((pos + ng + EPS) / pos);
    }
    for (int o = 32; o > 0; o >>= 1) s += __shfl_down(s, o);
    __shared__ float fl[8], vv[8];
    if (lane == 0) {
        float valid = (nfgt > 0 && nbg[t] > 0) ? 1.f : 0.f;
        fl[t] = valid * (s / fmaxf((float)nfgt, 1.f));
        vv[t] = valid;
    }
    __syncthreads();
    if (tid == 0) {
        float ls = 0.f, v = 0.f;
        for (int i = 0; i < T; ++i) { ls += fl[i]; v += vv[i]; }
        out_loss[0] = (v > 0.f) ? ls / fmaxf(v, 1.f) : 0.f;
    }
}

// ---------------------------------------------------------------------------
extern "C" void kernel_launch(void* const* d_in, const int* in_sizes, int n_in,
                              void* d_out, int out_size, void* d_ws, size_t ws_size,
                              hipStream_t stream) {
    const float* cur  = (const float*)d_in[0];
    const float* hist = (const float*)d_in[1];
    const float* feat = (const float*)d_in[2];
    float* out = (float*)d_out;   // labels[32768] ++ loss[1]

    char* ws = (char*)d_ws;
    bf16*  fpack   = (bf16*)ws;                           // T*CAP*C bf16 = 17.33 MB
    size_t off = (size_t)T * CAP * C * sizeof(bf16);      // 17334272
    float* negbuf  = (float*)(ws + off);  off += (size_t)T * N * 4;   // 131072
    float* posc    = (float*)(ws + off);  off += (size_t)T * N * 4;   // 131072
    int*   nfg     = (int*)(ws + off);    off += 8 * 4;
    int*   nbg     = (int*)(ws + off);

    pack_kernel<<<512, 256, 0, stream>>>(cur, hist, feat, out, negbuf, fpack,
                                         posc, nfg, nbg);
    sim_kernel<<<2176, 256, 0, stream>>>(fpack, nfg, nbg, negbuf);
    loss_kernel<<<1, 512, 0, stream>>>(negbuf, posc, nfg, nbg, out + 32768);
}